// Round 1
// baseline (66.575 us; speedup 1.0000x reference)
//
#include <hip/hip_runtime.h>
#include <math.h>

// One thread per 8x8 DLT system, exploiting the block structure:
//   y-row k:  U_k h0 + V_k h1 + h2           - Y_k h6 - Z_k h7 = up_k
//   x-row k:            U_k h3 + V_k h4 + h5 - W_k h6 - X_k h7 = vp_k
// with U=trunc(u), V=trunc(v), Y=trunc(up*u), Z=trunc(up*v),
//      W=trunc(vp*u), X=trunc(vp*v)  (reference's .long() truncation).
//
// Pivot safety (from earlier round): evaluate all four point-triples' dets,
// keep the one with max |det|, permute points so it sits in slots 0..2.
//
// R(this): all truncated quantities are exact small integers
// (|U|,|V| < 2^11, |Y..X| < 2^21, |d|,|q|,|det| < 2^24), so the dets,
// adjugate N, det and q are computed in int32 with full-rate 24-bit
// multiplies instead of half-rate f64 (f64 wave-op = 4 cyc vs 2 for int).
// f64 remains only where required for exactness/accuracy:
//   - the 16 products up*u etc. BEFORE truncation (f32 mul would round and
//     can flip trunc at integer boundaries),
//   - the reduced 2x2 solve (q*Y ~ 2^44, exact in f64),
//   - the back-substitution (non-integer up/vp enter).
// All replaced arithmetic is exact in both representations -> output is
// bit-identical to the previous all-f64 version.
__global__ __launch_bounds__(256) void TensorDlt_48215302865189_kernel(
    const float* __restrict__ x, const float* __restrict__ xp,
    float* __restrict__ out, int B) {
  int i = blockIdx.x * blockDim.x + threadIdx.x;
  if (i >= B) return;

  const float4* x4 = reinterpret_cast<const float4*>(x + (size_t)i * 8);
  float4 a0 = x4[0], a1 = x4[1];
  const float4* p4 = reinterpret_cast<const float4*>(xp + (size_t)i * 8);
  float4 c0 = p4[0], c1 = p4[1];

  float uf[4]  = {a0.x, a0.z, a1.x, a1.z};
  float vf[4]  = {a0.y, a0.w, a1.y, a1.w};
  float upf[4] = {c0.x, c0.z, c1.x, c1.z};
  float vpf[4] = {c0.y, c0.w, c1.y, c1.w};

  int U[4], V[4], Y[4], Z[4], W[4], X[4];
#pragma unroll
  for (int k = 0; k < 4; k++) {
    U[k] = (int)uf[k];                      // v_cvt_i32_f32 truncates toward 0
    V[k] = (int)vf[k];
    double ud = (double)uf[k], vd = (double)vf[k];
    double upd = (double)upf[k], vpd = (double)vpf[k];
    Y[k] = (int)(upd * ud);                 // exact f64 product, v_cvt_i32_f64
    Z[k] = (int)(upd * vd);
    W[k] = (int)(vpd * ud);
    X[k] = (int)(vpd * vd);
  }

  // Signed dets of the four point-triples (exact int32); de excludes point e.
  int d3 = __mul24(U[0], V[1] - V[2]) + __mul24(U[1], V[2] - V[0]) + __mul24(U[2], V[0] - V[1]);
  int d2 = __mul24(U[0], V[1] - V[3]) + __mul24(U[1], V[3] - V[0]) + __mul24(U[3], V[0] - V[1]);
  int d1 = __mul24(U[0], V[2] - V[3]) + __mul24(U[2], V[3] - V[0]) + __mul24(U[3], V[0] - V[2]);
  int d0 = __mul24(U[1], V[2] - V[3]) + __mul24(U[2], V[3] - V[1]) + __mul24(U[3], V[1] - V[2]);

  int e = 3;
  int bd = d3 < 0 ? -d3 : d3;
  int t;
  t = d2 < 0 ? -d2 : d2; if (t > bd) { e = 2; bd = t; }
  t = d1 < 0 ? -d1 : d1; if (t > bd) { e = 1; bd = t; }
  t = d0 < 0 ? -d0 : d0; if (t > bd) { e = 0; bd = t; }

  // Permute points so excluded point e lands in slot 3, kept triple in 0..2.
  // slot0 <- (e==0 ? 1 : 0); slot1 <- (e>=2 ? 1 : 2);
  // slot2 <- (e==3 ? 2 : 3); slot3 <- e.   All static indexing -> VGPRs.
#define PERM4(T, a)                                                          \
  {                                                                          \
    T p0 = (e == 0) ? a[1] : a[0];                                           \
    T p1 = (e >= 2) ? a[1] : a[2];                                           \
    T p2 = (e == 3) ? a[2] : a[3];                                           \
    T p3 = (e == 3) ? a[3] : (e == 2) ? a[2] : (e == 1) ? a[1] : a[0];       \
    a[0] = p0; a[1] = p1; a[2] = p2; a[3] = p3;                              \
  }
  PERM4(int, U); PERM4(int, V); PERM4(int, Y); PERM4(int, Z);
  PERM4(int, W); PERM4(int, X);
  PERM4(float, upf); PERM4(float, vpf);
#undef PERM4

  // Adjugate + det of M3 = [[U0,V0,1],[U1,V1,1],[U2,V2,1]] — exact int32.
  int N00 = V[1] - V[2], N01 = V[2] - V[0], N02 = V[0] - V[1];
  int N10 = U[2] - U[1], N11 = U[0] - U[2], N12 = U[1] - U[0];
  int N20 = __mul24(U[1], V[2]) - __mul24(V[1], U[2]);
  int N21 = __mul24(U[2], V[0]) - __mul24(V[2], U[0]);
  int N22 = __mul24(U[0], V[1]) - __mul24(V[0], U[1]);
  int det = __mul24(U[0], N00) + __mul24(V[0], N10) + N20;

  // q = (U3, V3, 1) * N  (scaled row-3 elimination weights) — exact int32.
  int q0 = __mul24(U[3], N00) + __mul24(V[3], N10) + N20;
  int q1 = __mul24(U[3], N01) + __mul24(V[3], N11) + N21;
  int q2 = __mul24(U[3], N02) + __mul24(V[3], N12) + N22;

  // Promote to f64 exactly where magnitudes exceed 2^31 or data is non-integer.
  double q0d = (double)q0, q1d = (double)q1, q2d = (double)q2;
  double detd = (double)det;
  double Y0 = (double)Y[0], Y1 = (double)Y[1], Y2 = (double)Y[2], Y3 = (double)Y[3];
  double Z0 = (double)Z[0], Z1 = (double)Z[1], Z2 = (double)Z[2], Z3 = (double)Z[3];
  double W0 = (double)W[0], W1 = (double)W[1], W2 = (double)W[2], W3 = (double)W[3];
  double X0 = (double)X[0], X1 = (double)X[1], X2 = (double)X[2], X3 = (double)X[3];
  double up0 = (double)upf[0], up1 = (double)upf[1], up2 = (double)upf[2], up3 = (double)upf[3];
  double vp0 = (double)vpf[0], vp1 = (double)vpf[1], vp2 = (double)vpf[2], vp3 = (double)vpf[3];

  // Reduced 2x2 in (h6, h7). Products ~2^44, exact in f64.
  double A1 = q0d * Y0 + q1d * Y1 + q2d * Y2 - detd * Y3;
  double B1 = q0d * Z0 + q1d * Z1 + q2d * Z2 - detd * Z3;
  double R1 = detd * up3 - (q0d * up0 + q1d * up1 + q2d * up2);
  double A2 = q0d * W0 + q1d * W1 + q2d * W2 - detd * W3;
  double B2 = q0d * X0 + q1d * X1 + q2d * X2 - detd * X3;
  double R2 = detd * vp3 - (q0d * vp0 + q1d * vp1 + q2d * vp2);

  double D2inv = 1.0 / (A1 * B2 - A2 * B1);
  double h6 = (R1 * B2 - R2 * B1) * D2inv;
  double h7 = (A1 * R2 - A2 * R1) * D2inv;

  // Back-substitution: M3 g1 = up + Cy g3, M3 g2 = vp + Cx g3.
  double detinv = 1.0 / detd;
  double N00d = (double)N00, N01d = (double)N01, N02d = (double)N02;
  double N10d = (double)N10, N11d = (double)N11, N12d = (double)N12;
  double N20d = (double)N20, N21d = (double)N21, N22d = (double)N22;

  double r0 = up0 + Y0 * h6 + Z0 * h7;
  double r1 = up1 + Y1 * h6 + Z1 * h7;
  double r2 = up2 + Y2 * h6 + Z2 * h7;
  double h0 = (N00d * r0 + N01d * r1 + N02d * r2) * detinv;
  double h1 = (N10d * r0 + N11d * r1 + N12d * r2) * detinv;
  double h2 = (N20d * r0 + N21d * r1 + N22d * r2) * detinv;

  double s0 = vp0 + W0 * h6 + X0 * h7;
  double s1 = vp1 + W1 * h6 + X1 * h7;
  double s2 = vp2 + W2 * h6 + X2 * h7;
  double h3 = (N00d * s0 + N01d * s1 + N02d * s2) * detinv;
  double h4 = (N10d * s0 + N11d * s1 + N12d * s2) * detinv;
  double h5 = (N20d * s0 + N21d * s1 + N22d * s2) * detinv;

  float* o = out + (size_t)i * 9;
  o[0] = (float)h0; o[1] = (float)h1; o[2] = (float)h2;
  o[3] = (float)h3; o[4] = (float)h4; o[5] = (float)h5;
  o[6] = (float)h6; o[7] = (float)h7; o[8] = 1.0f;
}

extern "C" void kernel_launch(void* const* d_in, const int* in_sizes, int n_in,
                              void* d_out, int out_size, void* d_ws, size_t ws_size,
                              hipStream_t stream) {
  const float* x  = (const float*)d_in[0];
  const float* xp = (const float*)d_in[1];
  float* out = (float*)d_out;
  int B = in_sizes[0] / 8;  // 262144
  int block = 256;
  int grid = (B + block - 1) / block;
  TensorDlt_48215302865189_kernel<<<grid, block, 0, stream>>>(x, xp, out, B);
}